// Round 1
// baseline (1388.129 us; speedup 1.0000x reference)
//
#include <hip/hip_runtime.h>

// MoE FFN: top-2 of 8 routed SwiGLU experts + shared expert.
// T=4096 tokens, H=1024, F=2752. fp32 in/out, bf16 MFMA internally.
// R1: global_load_lds(16B) staging w/ XOR-swizzled LDS chunks; m-innermost grid.

#define Hdim 1024
#define Fdim 2752
#define Edim 8
#define Tdim 4096

typedef unsigned short u16;
typedef __bf16 bf16x8 __attribute__((ext_vector_type(8)));
typedef float f32x4 __attribute__((ext_vector_type(4)));

#define MFMA16(a, b, c) __builtin_amdgcn_mfma_f32_16x16x32_bf16(a, b, c, 0, 0, 0)

__device__ __forceinline__ u16 f2bf(float f) {  // fp32 -> bf16 bits, RNE
  unsigned u = __float_as_uint(f);
  u += 0x7fffu + ((u >> 16) & 1u);
  return (u16)(u >> 16);
}

// async global->LDS, 16B per lane. LDS dest is wave-uniform base + lane*16.
__device__ __forceinline__ void gload16(const u16* g, u16* l) {
  __builtin_amdgcn_global_load_lds((const __attribute__((address_space(1))) void*)g,
                                   (__attribute__((address_space(3))) void*)l, 16, 0, 0);
}

// ---------- transpose + convert: src[R][C] fp32 -> dst[C][R] bf16 ----------
__global__ __launch_bounds__(256) void transpose_k(const float* __restrict__ src,
                                                   u16* __restrict__ dst, int R, int C) {
  __shared__ float tile[64][65];
  const size_t zoff = (size_t)blockIdx.z * R * C;
  src += zoff; dst += zoff;
  const int r0 = blockIdx.y * 64, c0 = blockIdx.x * 64;
  const int tx = threadIdx.x & 63, ty = threadIdx.x >> 6;
#pragma unroll
  for (int i = 0; i < 16; i++) {
    int row = ty * 16 + i;
    tile[row][tx] = src[(size_t)(r0 + row) * C + (c0 + tx)];
  }
  __syncthreads();
#pragma unroll
  for (int i = 0; i < 16; i++) {
    int crow = ty * 16 + i;
    dst[(size_t)(c0 + crow) * R + (r0 + tx)] = f2bf(tile[tx][crow]);
  }
}

// ---------- gate: exact fp32 softmax top-2, build gather lists; x -> bf16 ----------
__global__ __launch_bounds__(64) void gate_k(const float* __restrict__ x,
                                             const float* __restrict__ gw,
                                             u16* __restrict__ xbf,
                                             int* __restrict__ counts,
                                             int* __restrict__ tok,
                                             float* __restrict__ wt) {
  const int t = blockIdx.x, lane = threadIdx.x;
  const float* xr = x + (size_t)t * Hdim;
  float acc[Edim];
#pragma unroll
  for (int e = 0; e < Edim; e++) acc[e] = 0.f;
  for (int i = 0; i < Hdim / 64; i++) {
    int idx = i * 64 + lane;
    float xv = xr[idx];
    xbf[(size_t)t * Hdim + idx] = f2bf(xv);
#pragma unroll
    for (int e = 0; e < Edim; e++) acc[e] += xv * gw[e * Hdim + idx];
  }
#pragma unroll
  for (int e = 0; e < Edim; e++)
    for (int o = 32; o > 0; o >>= 1) acc[e] += __shfl_xor(acc[e], o, 64);
  if (lane == 0) {
    float m = acc[0];
    for (int e = 1; e < Edim; e++) m = fmaxf(m, acc[e]);
    float p[Edim], ssum = 0.f;
    for (int e = 0; e < Edim; e++) { p[e] = expf(acc[e] - m); ssum += p[e]; }
    // top-2 on logits (monotone w/ softmax); strict > keeps lowest index on ties (jax top_k)
    int i1 = 0; float l1 = acc[0];
    for (int e = 1; e < Edim; e++) if (acc[e] > l1) { l1 = acc[e]; i1 = e; }
    int i2 = -1; float l2 = -1e30f;
    for (int e = 0; e < Edim; e++) if (e != i1 && acc[e] > l2) { l2 = acc[e]; i2 = e; }
    float s1 = p[i1] / ssum, s2 = p[i2] / ssum;
    float den = s1 + s2 + 1e-20f;
    float w1 = s1 / den, w2 = s2 / den;
    int p1 = atomicAdd(&counts[i1], 1);
    tok[i1 * Tdim + p1] = t; wt[i1 * Tdim + p1] = w1;
    int p2 = atomicAdd(&counts[i2], 1);
    tok[i2 * Tdim + p2] = t; wt[i2 * Tdim + p2] = w2;
  }
}

__global__ void scan_k(const int* __restrict__ counts, int* __restrict__ offs) {
  if (threadIdx.x == 0) {
    int a = 0;
    for (int e = 0; e < Edim; e++) { offs[e] = a; a += counts[e]; }
    offs[Edim] = a;
  }
}

// LDS tile layout: rows of 32 u16 = 64 B = 4 chunks of 16 B.
// chunk (r,c) stored at slot (r, c ^ ((r>>1)&3)).  Involution; linear dest for
// global_load_lds (pre-swizzled SOURCE address), swizzled ds_read address.
// b128 read of 16 rows at fixed c hits each 4-bank group exactly 2x -> free.

// ---------- GEMM1: s = silu(X@Wg) * (X@Wu), gathered rows, bf16 out ----------
// Block: 128 rows x 64 f-cols (both G and U). 4 waves, each 64x32 of both.
template <bool GATHER>
__global__ __launch_bounds__(256) void gemm1_k(const u16* __restrict__ xbf,
                                               const u16* __restrict__ wg_t,  // [E][F][H] bf16
                                               const u16* __restrict__ wu_t,
                                               const int* __restrict__ tok_list,
                                               const int* __restrict__ counts,
                                               const int* __restrict__ offs,
                                               u16* __restrict__ s_out,
                                               int e_base) {
  const int e = e_base + blockIdx.z;
  const int nrows = GATHER ? counts[e] : Tdim;
  const int m0 = blockIdx.x * 128;   // m innermost: co-resident blocks share B
  if (m0 >= nrows) return;
  const int n0 = blockIdx.y * 64;
  const int srow0 = GATHER ? (offs[e] + m0) : m0;

  __shared__ __align__(16) u16 lA[128 * 32];   // 512 chunks
  __shared__ __align__(16) u16 lBG[64 * 32];   // 256 chunks
  __shared__ __align__(16) u16 lBU[64 * 32];

  const int tid = threadIdx.x;
  const int wave = tid >> 6, lane = tid & 63;

  // ---- staging geometry ----
  const int ch = wave * 64 + lane;                 // [0,256)
  const int sr0 = ch >> 2;                         // [0,64)
  const int sc = (ch & 3) ^ ((sr0 >> 1) & 3);      // swizzled source chunk (same for sr0+64)

  int ar0 = m0 + sr0;      if (ar0 > nrows - 1) ar0 = nrows - 1;
  int ar1 = m0 + sr0 + 64; if (ar1 > nrows - 1) ar1 = nrows - 1;
  const int tk0 = GATHER ? tok_list[(size_t)e * Tdim + ar0] : ar0;
  const int tk1 = GATHER ? tok_list[(size_t)e * Tdim + ar1] : ar1;
  const u16* aSrc0 = xbf + (size_t)tk0 * Hdim + sc * 8;
  const u16* aSrc1 = xbf + (size_t)tk1 * Hdim + sc * 8;
  u16* aDst0 = lA + wave * 512;            // chunks [wave*64, wave*64+64)
  u16* aDst1 = lA + 2048 + wave * 512;     // chunks [256+wave*64, ...)
  const u16* bgSrc = wg_t + (size_t)e * Fdim * Hdim + (size_t)(n0 + sr0) * Hdim + sc * 8;
  const u16* buSrc = wu_t + (size_t)e * Fdim * Hdim + (size_t)(n0 + sr0) * Hdim + sc * 8;
  u16* bgDst = lBG + wave * 512;
  u16* buDst = lBU + wave * 512;

  // ---- compute geometry ----
  const int wm = (wave & 1) * 64, wn = (wave >> 1) * 32;
  const int lrow = lane & 15, lc = lane >> 4;      // fragment row-in-16, K-chunk

  const u16* pA[4]; const u16* pBG[2]; const u16* pBU[2];
#pragma unroll
  for (int mt = 0; mt < 4; mt++) {
    int r = wm + mt * 16 + lrow;
    pA[mt] = lA + (r * 4 + (lc ^ ((r >> 1) & 3))) * 8;
  }
#pragma unroll
  for (int nt = 0; nt < 2; nt++) {
    int r = wn + nt * 16 + lrow;
    int off = (r * 4 + (lc ^ ((r >> 1) & 3))) * 8;
    pBG[nt] = lBG + off;
    pBU[nt] = lBU + off;
  }

  f32x4 zero = {0.f, 0.f, 0.f, 0.f};
  f32x4 accG[4][2], accU[4][2];
#pragma unroll
  for (int mt = 0; mt < 4; mt++)
#pragma unroll
    for (int nt = 0; nt < 2; nt++) { accG[mt][nt] = zero; accU[mt][nt] = zero; }

  for (int k0 = 0; k0 < Hdim; k0 += 32) {
    gload16(aSrc0 + k0, aDst0);
    gload16(aSrc1 + k0, aDst1);
    gload16(bgSrc + k0, bgDst);
    gload16(buSrc + k0, buDst);
    __syncthreads();   // drains vmcnt: staged tile visible
    bf16x8 af[4], bg[2], bu[2];
#pragma unroll
    for (int mt = 0; mt < 4; mt++) af[mt] = *(const bf16x8*)pA[mt];
#pragma unroll
    for (int nt = 0; nt < 2; nt++) { bg[nt] = *(const bf16x8*)pBG[nt]; bu[nt] = *(const bf16x8*)pBU[nt]; }
#pragma unroll
    for (int mt = 0; mt < 4; mt++)
#pragma unroll
      for (int nt = 0; nt < 2; nt++) {
        accG[mt][nt] = MFMA16(af[mt], bg[nt], accG[mt][nt]);
        accU[mt][nt] = MFMA16(af[mt], bu[nt], accU[mt][nt]);
      }
    __syncthreads();   // all reads done before next-step overwrite
  }
  // epilogue: silu(g)*u -> bf16
#pragma unroll
  for (int mt = 0; mt < 4; mt++)
#pragma unroll
    for (int nt = 0; nt < 2; nt++)
#pragma unroll
      for (int r = 0; r < 4; r++) {
        int row = wm + mt * 16 + (lane >> 4) * 4 + r;
        if (m0 + row < nrows) {
          float g = accG[mt][nt][r], u = accU[mt][nt][r];
          float sv = g * (1.0f / (1.0f + __expf(-g))) * u;
          s_out[(size_t)(srow0 + row) * Fdim + (n0 + wn + nt * 16 + (lane & 15))] = f2bf(sv);
        }
      }
}

// ---------- GEMM2: Y = s @ Wd; routed: atomicAdd(out, w*Y); shared: store ----------
template <bool GATHER>
__global__ __launch_bounds__(256) void gemm2_k(const u16* __restrict__ s_in,
                                               const u16* __restrict__ wd_t,  // [E][H][F] bf16
                                               const int* __restrict__ tok_list,
                                               const int* __restrict__ counts,
                                               const int* __restrict__ offs,
                                               const float* __restrict__ wt_list,
                                               float* __restrict__ out,
                                               int e_base) {
  const int e = e_base + blockIdx.z;
  const int nrows = GATHER ? counts[e] : Tdim;
  const int m0 = blockIdx.x * 128;
  if (m0 >= nrows) return;
  const int n0 = blockIdx.y * 128;

  __shared__ __align__(16) u16 lA[128 * 32];
  __shared__ __align__(16) u16 lB[128 * 32];

  const int tid = threadIdx.x;
  const int wave = tid >> 6, lane = tid & 63;

  const int ch = wave * 64 + lane;
  const int sr0 = ch >> 2;
  const int sc = (ch & 3) ^ ((sr0 >> 1) & 3);

  int ar0 = m0 + sr0;      if (ar0 > nrows - 1) ar0 = nrows - 1;
  int ar1 = m0 + sr0 + 64; if (ar1 > nrows - 1) ar1 = nrows - 1;
  const size_t as0 = GATHER ? (size_t)(offs[e] + ar0) : (size_t)ar0;  // s rows contiguous
  const size_t as1 = GATHER ? (size_t)(offs[e] + ar1) : (size_t)ar1;
  const u16* aSrc0 = s_in + as0 * Fdim + sc * 8;
  const u16* aSrc1 = s_in + as1 * Fdim + sc * 8;
  u16* aDst0 = lA + wave * 512;
  u16* aDst1 = lA + 2048 + wave * 512;
  const u16* bSrc0 = wd_t + (size_t)e * Hdim * Fdim + (size_t)(n0 + sr0) * Fdim + sc * 8;
  const u16* bSrc1 = wd_t + (size_t)e * Hdim * Fdim + (size_t)(n0 + sr0 + 64) * Fdim + sc * 8;
  u16* bDst0 = lB + wave * 512;
  u16* bDst1 = lB + 2048 + wave * 512;

  const int wm = (wave & 1) * 64, wn = (wave >> 1) * 64;
  const int lrow = lane & 15, lc = lane >> 4;

  const u16* pA[4]; const u16* pB[4];
#pragma unroll
  for (int mt = 0; mt < 4; mt++) {
    int r = wm + mt * 16 + lrow;
    pA[mt] = lA + (r * 4 + (lc ^ ((r >> 1) & 3))) * 8;
  }
#pragma unroll
  for (int nt = 0; nt < 4; nt++) {
    int r = wn + nt * 16 + lrow;
    pB[nt] = lB + (r * 4 + (lc ^ ((r >> 1) & 3))) * 8;
  }

  f32x4 zero = {0.f, 0.f, 0.f, 0.f};
  f32x4 acc[4][4];
#pragma unroll
  for (int mt = 0; mt < 4; mt++)
#pragma unroll
    for (int nt = 0; nt < 4; nt++) acc[mt][nt] = zero;

  for (int k0 = 0; k0 < Fdim; k0 += 32) {
    gload16(aSrc0 + k0, aDst0);
    gload16(aSrc1 + k0, aDst1);
    gload16(bSrc0 + k0, bDst0);
    gload16(bSrc1 + k0, bDst1);
    __syncthreads();
    bf16x8 af[4], bf[4];
#pragma unroll
    for (int mt = 0; mt < 4; mt++) af[mt] = *(const bf16x8*)pA[mt];
#pragma unroll
    for (int nt = 0; nt < 4; nt++) bf[nt] = *(const bf16x8*)pB[nt];
#pragma unroll
    for (int mt = 0; mt < 4; mt++)
#pragma unroll
      for (int nt = 0; nt < 4; nt++)
        acc[mt][nt] = MFMA16(af[mt], bf[nt], acc[mt][nt]);
    __syncthreads();
  }
#pragma unroll
  for (int mt = 0; mt < 4; mt++)
#pragma unroll
    for (int nt = 0; nt < 4; nt++)
#pragma unroll
      for (int r = 0; r < 4; r++) {
        int row = wm + mt * 16 + (lane >> 4) * 4 + r;
        if (m0 + row < nrows) {
          int col = n0 + wn + nt * 16 + (lane & 15);
          float v = acc[mt][nt][r];
          if (GATHER) {
            int t = tok_list[(size_t)e * Tdim + m0 + row];
            float w = wt_list[(size_t)e * Tdim + m0 + row];
            atomicAdd(out + (size_t)t * Hdim + col, v * w);
          } else {
            out[(size_t)(m0 + row) * Hdim + col] = v;
          }
        }
      }
}

// ---------------- launch ----------------
extern "C" void kernel_launch(void* const* d_in, const int* in_sizes, int n_in,
                              void* d_out, int out_size, void* d_ws, size_t ws_size,
                              hipStream_t stream) {
  const float* x      = (const float*)d_in[0];
  const float* gate_w = (const float*)d_in[1];
  const float* wg     = (const float*)d_in[2];
  const float* wu     = (const float*)d_in[3];
  const float* wd     = (const float*)d_in[4];
  const float* sg     = (const float*)d_in[5];
  const float* su     = (const float*)d_in[6];
  const float* sd     = (const float*)d_in[7];
  float* out = (float*)d_out;
  char* ws = (char*)d_ws;

  // common small buffers
  constexpr size_t O_COUNTS = 0;     // 64 B
  constexpr size_t O_ZOFF   = 64;    // 64 B of zeros (phased-mode "offs")
  constexpr size_t O_OFFS   = 128;   // 64 B
  constexpr size_t O_TOK    = 256;
  constexpr size_t O_WT     = O_TOK + sizeof(int) * (size_t)Edim * Tdim;
  constexpr size_t O_XBF    = O_WT + sizeof(float) * (size_t)Edim * Tdim;
  constexpr size_t O_AFTER  = O_XBF + 2ull * Tdim * Hdim;

  constexpr size_t SZ_EHF = 2ull * Hdim * Fdim;           // one expert matrix, bf16
  // batched layout
  constexpr size_t B_WGT = O_AFTER;
  constexpr size_t B_WUT = B_WGT + SZ_EHF * Edim;
  constexpr size_t B_WDT = B_WUT + SZ_EHF * Edim;
  constexpr size_t B_SGT = B_WDT + SZ_EHF * Edim;
  constexpr size_t B_SUT = B_SGT + SZ_EHF;
  constexpr size_t B_SDT = B_SUT + SZ_EHF;
  constexpr size_t B_SRT = B_SDT + SZ_EHF;                // routed s: [2T][F]
  constexpr size_t B_SSH = B_SRT + 2ull * 2 * Tdim * Fdim;
  constexpr size_t B_END = B_SSH + 2ull * Tdim * Fdim;    // ~218 MiB

  // phased layout (per-expert reuse)
  constexpr size_t P_A = O_AFTER;
  constexpr size_t P_B = P_A + SZ_EHF;
  constexpr size_t P_D = P_B + SZ_EHF;
  constexpr size_t P_S = P_D + SZ_EHF;                    // s: [T][F]

  int*   counts = (int*)(ws + O_COUNTS);
  int*   zoff   = (int*)(ws + O_ZOFF);
  int*   offs   = (int*)(ws + O_OFFS);
  int*   tok    = (int*)(ws + O_TOK);
  float* wt     = (float*)(ws + O_WT);
  u16*   xbf    = (u16*)(ws + O_XBF);

  hipMemsetAsync(ws, 0, 256, stream);  // zero counts + zoff (+offs, rewritten by scan)
  gate_k<<<Tdim, 64, 0, stream>>>(x, gate_w, xbf, counts, tok, wt);
  scan_k<<<1, 64, 0, stream>>>(counts, offs);

  if (ws_size >= B_END) {
    // ---------------- batched path ----------------
    u16* wg_t = (u16*)(ws + B_WGT);
    u16* wu_t = (u16*)(ws + B_WUT);
    u16* wd_t = (u16*)(ws + B_WDT);
    u16* sg_t = (u16*)(ws + B_SGT);
    u16* su_t = (u16*)(ws + B_SUT);
    u16* sd_t = (u16*)(ws + B_SDT);
    u16* s_rt = (u16*)(ws + B_SRT);
    u16* s_sh = (u16*)(ws + B_SSH);

    transpose_k<<<dim3(Fdim / 64, Hdim / 64, Edim), 256, 0, stream>>>(wg, wg_t, Hdim, Fdim);
    transpose_k<<<dim3(Fdim / 64, Hdim / 64, Edim), 256, 0, stream>>>(wu, wu_t, Hdim, Fdim);
    transpose_k<<<dim3(Hdim / 64, Fdim / 64, Edim), 256, 0, stream>>>(wd, wd_t, Fdim, Hdim);
    transpose_k<<<dim3(Fdim / 64, Hdim / 64, 1), 256, 0, stream>>>(sg, sg_t, Hdim, Fdim);
    transpose_k<<<dim3(Fdim / 64, Hdim / 64, 1), 256, 0, stream>>>(su, su_t, Hdim, Fdim);
    transpose_k<<<dim3(Hdim / 64, Fdim / 64, 1), 256, 0, stream>>>(sd, sd_t, Fdim, Hdim);

    gemm1_k<false><<<dim3(Tdim / 128, Fdim / 64, 1), 256, 0, stream>>>(
        xbf, sg_t, su_t, tok, counts, offs, s_sh, 0);
    gemm1_k<true><<<dim3(Tdim / 128, Fdim / 64, Edim), 256, 0, stream>>>(
        xbf, wg_t, wu_t, tok, counts, offs, s_rt, 0);

    gemm2_k<false><<<dim3(Tdim / 128, Hdim / 128, 1), 256, 0, stream>>>(
        s_sh, sd_t, tok, counts, offs, wt, out, 0);
    gemm2_k<true><<<dim3(Tdim / 128, Hdim / 128, Edim), 256, 0, stream>>>(
        s_rt, wd_t, tok, counts, offs, wt, out, 0);
  } else {
    // ---------------- phased path (per-expert buffer reuse, ~46 MiB) ----------------
    u16* A = (u16*)(ws + P_A);
    u16* Bb = (u16*)(ws + P_B);
    u16* D = (u16*)(ws + P_D);
    u16* S = (u16*)(ws + P_S);

    // shared expert
    transpose_k<<<dim3(Fdim / 64, Hdim / 64, 1), 256, 0, stream>>>(sg, A, Hdim, Fdim);
    transpose_k<<<dim3(Fdim / 64, Hdim / 64, 1), 256, 0, stream>>>(su, Bb, Hdim, Fdim);
    transpose_k<<<dim3(Hdim / 64, Fdim / 64, 1), 256, 0, stream>>>(sd, D, Fdim, Hdim);
    gemm1_k<false><<<dim3(Tdim / 128, Fdim / 64, 1), 256, 0, stream>>>(
        xbf, A, Bb, tok, counts, offs, S, 0);
    gemm2_k<false><<<dim3(Tdim / 128, Hdim / 128, 1), 256, 0, stream>>>(
        S, D, tok, counts, offs, wt, out, 0);

    // routed experts, one at a time; zoff (all zeros) makes S per-expert-local.
    for (int e = 0; e < Edim; e++) {
      const size_t weoff = (size_t)e * Hdim * Fdim;
      transpose_k<<<dim3(Fdim / 64, Hdim / 64, 1), 256, 0, stream>>>(wg + weoff, A, Hdim, Fdim);
      transpose_k<<<dim3(Fdim / 64, Hdim / 64, 1), 256, 0, stream>>>(wu + weoff, Bb, Hdim, Fdim);
      transpose_k<<<dim3(Hdim / 64, Fdim / 64, 1), 256, 0, stream>>>(wd + weoff, D, Fdim, Hdim);
      // kernel reads counts[e]/tok[e*T..] via e = e_base + 0; S indexed from 0 via zoff
      gemm1_k<true><<<dim3(Tdim / 128, Fdim / 64, 1), 256, 0, stream>>>(
          xbf, A - weoff, Bb - weoff, tok, counts, zoff, S, e);
      gemm2_k<true><<<dim3(Tdim / 128, Hdim / 128, 1), 256, 0, stream>>>(
          S, D - weoff, tok, counts, zoff, wt, out, e);
    }
  }

  (void)in_sizes; (void)n_in; (void)out_size; (void)ws_size;
}

// Round 3
// 1360.337 us; speedup vs baseline: 1.0204x; 1.0204x over previous
//
#include <hip/hip_runtime.h>

// MoE FFN: top-2 of 8 routed SwiGLU experts + shared expert.
// T=4096 tokens, H=1024, F=2752. fp32 in/out, bf16 MFMA internally.
// R3 (= R2 re-run; container flake): 2-phase double-buffered global_load_lds
// pipeline (stage k+1 || compute k), XOR-swizzled LDS chunks (0 conflicts,
// verified R1), one barrier per K-step.

#define Hdim 1024
#define Fdim 2752
#define Edim 8
#define Tdim 4096

typedef unsigned short u16;
typedef __bf16 bf16x8 __attribute__((ext_vector_type(8)));
typedef float f32x4 __attribute__((ext_vector_type(4)));

#define MFMA16(a, b, c) __builtin_amdgcn_mfma_f32_16x16x32_bf16(a, b, c, 0, 0, 0)

__device__ __forceinline__ u16 f2bf(float f) {  // fp32 -> bf16 bits, RNE
  unsigned u = __float_as_uint(f);
  u += 0x7fffu + ((u >> 16) & 1u);
  return (u16)(u >> 16);
}

// async global->LDS, 16B per lane. LDS dest is wave-uniform base + lane*16.
__device__ __forceinline__ void gload16(const u16* g, u16* l) {
  __builtin_amdgcn_global_load_lds((const __attribute__((address_space(1))) void*)g,
                                   (__attribute__((address_space(3))) void*)l, 16, 0, 0);
}

// ---------- transpose + convert: src[R][C] fp32 -> dst[C][R] bf16 ----------
__global__ __launch_bounds__(256) void transpose_k(const float* __restrict__ src,
                                                   u16* __restrict__ dst, int R, int C) {
  __shared__ float tile[64][65];
  const size_t zoff = (size_t)blockIdx.z * R * C;
  src += zoff; dst += zoff;
  const int r0 = blockIdx.y * 64, c0 = blockIdx.x * 64;
  const int tx = threadIdx.x & 63, ty = threadIdx.x >> 6;
#pragma unroll
  for (int i = 0; i < 16; i++) {
    int row = ty * 16 + i;
    tile[row][tx] = src[(size_t)(r0 + row) * C + (c0 + tx)];
  }
  __syncthreads();
#pragma unroll
  for (int i = 0; i < 16; i++) {
    int crow = ty * 16 + i;
    dst[(size_t)(c0 + crow) * R + (r0 + tx)] = f2bf(tile[tx][crow]);
  }
}

// ---------- gate: exact fp32 softmax top-2, build gather lists; x -> bf16 ----------
__global__ __launch_bounds__(64) void gate_k(const float* __restrict__ x,
                                             const float* __restrict__ gw,
                                             u16* __restrict__ xbf,
                                             int* __restrict__ counts,
                                             int* __restrict__ tok,
                                             float* __restrict__ wt) {
  const int t = blockIdx.x, lane = threadIdx.x;
  const float* xr = x + (size_t)t * Hdim;
  float acc[Edim];
#pragma unroll
  for (int e = 0; e < Edim; e++) acc[e] = 0.f;
  for (int i = 0; i < Hdim / 64; i++) {
    int idx = i * 64 + lane;
    float xv = xr[idx];
    xbf[(size_t)t * Hdim + idx] = f2bf(xv);
#pragma unroll
    for (int e = 0; e < Edim; e++) acc[e] += xv * gw[e * Hdim + idx];
  }
#pragma unroll
  for (int e = 0; e < Edim; e++)
    for (int o = 32; o > 0; o >>= 1) acc[e] += __shfl_xor(acc[e], o, 64);
  if (lane == 0) {
    float m = acc[0];
    for (int e = 1; e < Edim; e++) m = fmaxf(m, acc[e]);
    float p[Edim], ssum = 0.f;
    for (int e = 0; e < Edim; e++) { p[e] = expf(acc[e] - m); ssum += p[e]; }
    // top-2 on logits (monotone w/ softmax); strict > keeps lowest index on ties (jax top_k)
    int i1 = 0; float l1 = acc[0];
    for (int e = 1; e < Edim; e++) if (acc[e] > l1) { l1 = acc[e]; i1 = e; }
    int i2 = -1; float l2 = -1e30f;
    for (int e = 0; e < Edim; e++) if (e != i1 && acc[e] > l2) { l2 = acc[e]; i2 = e; }
    float s1 = p[i1] / ssum, s2 = p[i2] / ssum;
    float den = s1 + s2 + 1e-20f;
    float w1 = s1 / den, w2 = s2 / den;
    int p1 = atomicAdd(&counts[i1], 1);
    tok[i1 * Tdim + p1] = t; wt[i1 * Tdim + p1] = w1;
    int p2 = atomicAdd(&counts[i2], 1);
    tok[i2 * Tdim + p2] = t; wt[i2 * Tdim + p2] = w2;
  }
}

__global__ void scan_k(const int* __restrict__ counts, int* __restrict__ offs) {
  if (threadIdx.x == 0) {
    int a = 0;
    for (int e = 0; e < Edim; e++) { offs[e] = a; a += counts[e]; }
    offs[Edim] = a;
  }
}

// LDS tile layout: rows of 32 u16 = 64 B = 4 chunks of 16 B.
// chunk (r,c) stored at slot (r, c ^ ((r>>1)&3)).  Involution; linear dest for
// global_load_lds (pre-swizzled SOURCE address), swizzled ds_read address.
// Verified 0 bank conflicts in R1.

// ---------- GEMM1: s = silu(X@Wg) * (X@Wu), gathered rows, bf16 out ----------
// Block: 128 rows x 64 f-cols (both G and U). 4 waves, each 64x32 of both.
// Double-buffered: stage tile k+1 while computing tile k; 1 barrier per K-step.
template <bool GATHER>
__global__ __launch_bounds__(256) void gemm1_k(const u16* __restrict__ xbf,
                                               const u16* __restrict__ wg_t,  // [E][F][H] bf16
                                               const u16* __restrict__ wu_t,
                                               const int* __restrict__ tok_list,
                                               const int* __restrict__ counts,
                                               const int* __restrict__ offs,
                                               u16* __restrict__ s_out,
                                               int e_base) {
  const int e = e_base + blockIdx.z;
  const int nrows = GATHER ? counts[e] : Tdim;
  const int m0 = blockIdx.x * 128;   // m innermost: co-resident blocks share B
  if (m0 >= nrows) return;
  const int n0 = blockIdx.y * 64;
  const int srow0 = GATHER ? (offs[e] + m0) : m0;

  __shared__ __align__(16) u16 lA[2 * 128 * 32];   // 2 x 8 KB
  __shared__ __align__(16) u16 lBG[2 * 64 * 32];   // 2 x 4 KB
  __shared__ __align__(16) u16 lBU[2 * 64 * 32];

  const int tid = threadIdx.x;
  const int wave = tid >> 6, lane = tid & 63;

  // ---- staging geometry ----
  const int ch = wave * 64 + lane;                 // [0,256)
  const int sr0 = ch >> 2;                         // [0,64)
  const int sc = (ch & 3) ^ ((sr0 >> 1) & 3);      // swizzled source chunk
  const int aOffW = wave * 512;                    // wave-uniform LDS elem offset

  int ar0 = m0 + sr0;      if (ar0 > nrows - 1) ar0 = nrows - 1;
  int ar1 = m0 + sr0 + 64; if (ar1 > nrows - 1) ar1 = nrows - 1;
  const int tk0 = GATHER ? tok_list[(size_t)e * Tdim + ar0] : ar0;
  const int tk1 = GATHER ? tok_list[(size_t)e * Tdim + ar1] : ar1;
  const u16* aSrc0 = xbf + (size_t)tk0 * Hdim + sc * 8;
  const u16* aSrc1 = xbf + (size_t)tk1 * Hdim + sc * 8;
  const u16* bgSrc = wg_t + (size_t)e * Fdim * Hdim + (size_t)(n0 + sr0) * Hdim + sc * 8;
  const u16* buSrc = wu_t + (size_t)e * Fdim * Hdim + (size_t)(n0 + sr0) * Hdim + sc * 8;

  // ---- compute geometry ----
  const int wm = (wave & 1) * 64, wn = (wave >> 1) * 32;
  const int lrow = lane & 15, lc = lane >> 4;      // fragment row-in-16, K-chunk

  int oA[4], oB[2];
#pragma unroll
  for (int mt = 0; mt < 4; mt++) {
    int r = wm + mt * 16 + lrow;
    oA[mt] = (r * 4 + (lc ^ ((r >> 1) & 3))) * 8;
  }
#pragma unroll
  for (int nt = 0; nt < 2; nt++) {
    int r = wn + nt * 16 + lrow;
    oB[nt] = (r * 4 + (lc ^ ((r >> 1) & 3))) * 8;
  }

  f32x4 zero = {0.f, 0.f, 0.f, 0.f};
  f32x4 accG[4][2], accU[4][2];
#pragma unroll
  for (int mt = 0; mt < 4; mt++)
#pragma unroll
    for (int nt = 0; nt < 2; nt++) { accG[mt][nt] = zero; accU[mt][nt] = zero; }

#define STAGE1(buf, k)                                          \
  do {                                                          \
    gload16(aSrc0 + (k), lA + (buf) * 4096 + aOffW);            \
    gload16(aSrc1 + (k), lA + (buf) * 4096 + 2048 + aOffW);     \
    gload16(bgSrc + (k), lBG + (buf) * 2048 + aOffW);           \
    gload16(buSrc + (k), lBU + (buf) * 2048 + aOffW);           \
  } while (0)

#define COMP1(buf)                                              \
  do {                                                          \
    const u16* bA = lA + (buf) * 4096;                          \
    const u16* bG = lBG + (buf) * 2048;                         \
    const u16* bU = lBU + (buf) * 2048;                         \
    bf16x8 af[4], bg[2], bu[2];                                 \
    _Pragma("unroll")                                           \
    for (int mt = 0; mt < 4; mt++) af[mt] = *(const bf16x8*)(bA + oA[mt]); \
    _Pragma("unroll")                                           \
    for (int nt = 0; nt < 2; nt++) {                            \
      bg[nt] = *(const bf16x8*)(bG + oB[nt]);                   \
      bu[nt] = *(const bf16x8*)(bU + oB[nt]);                   \
    }                                                           \
    _Pragma("unroll")                                           \
    for (int mt = 0; mt < 4; mt++)                              \
      _Pragma("unroll")                                         \
      for (int nt = 0; nt < 2; nt++) {                          \
        accG[mt][nt] = MFMA16(af[mt], bg[nt], accG[mt][nt]);    \
        accU[mt][nt] = MFMA16(af[mt], bu[nt], accU[mt][nt]);    \
      }                                                         \
  } while (0)

  // prologue: stage tile 0, drain
  STAGE1(0, 0);
  __syncthreads();
  int cur = 0;
  // main loop: issue stage of k+1 FIRST, then compute k, then drain both
  for (int k0 = 0; k0 < Hdim - 32; k0 += 32) {
    STAGE1(cur ^ 1, k0 + 32);
    COMP1(cur);
    __syncthreads();   // vmcnt(0)+lgkmcnt(0)+barrier: prefetch landed, reads done
    cur ^= 1;
  }
  COMP1(cur);  // epilogue: last tile, no prefetch

#undef STAGE1
#undef COMP1

  // epilogue: silu(g)*u -> bf16
#pragma unroll
  for (int mt = 0; mt < 4; mt++)
#pragma unroll
    for (int nt = 0; nt < 2; nt++)
#pragma unroll
      for (int r = 0; r < 4; r++) {
        int row = wm + mt * 16 + (lane >> 4) * 4 + r;
        if (m0 + row < nrows) {
          float g = accG[mt][nt][r], u = accU[mt][nt][r];
          float sv = g * (1.0f / (1.0f + __expf(-g))) * u;
          s_out[(size_t)(srow0 + row) * Fdim + (n0 + wn + nt * 16 + (lane & 15))] = f2bf(sv);
        }
      }
}

// ---------- GEMM2: Y = s @ Wd; routed: atomicAdd(out, w*Y); shared: store ----------
template <bool GATHER>
__global__ __launch_bounds__(256) void gemm2_k(const u16* __restrict__ s_in,
                                               const u16* __restrict__ wd_t,  // [E][H][F] bf16
                                               const int* __restrict__ tok_list,
                                               const int* __restrict__ counts,
                                               const int* __restrict__ offs,
                                               const float* __restrict__ wt_list,
                                               float* __restrict__ out,
                                               int e_base) {
  const int e = e_base + blockIdx.z;
  const int nrows = GATHER ? counts[e] : Tdim;
  const int m0 = blockIdx.x * 128;
  if (m0 >= nrows) return;
  const int n0 = blockIdx.y * 128;

  __shared__ __align__(16) u16 lA[2 * 128 * 32];
  __shared__ __align__(16) u16 lB[2 * 128 * 32];

  const int tid = threadIdx.x;
  const int wave = tid >> 6, lane = tid & 63;

  const int ch = wave * 64 + lane;
  const int sr0 = ch >> 2;
  const int sc = (ch & 3) ^ ((sr0 >> 1) & 3);
  const int aOffW = wave * 512;

  int ar0 = m0 + sr0;      if (ar0 > nrows - 1) ar0 = nrows - 1;
  int ar1 = m0 + sr0 + 64; if (ar1 > nrows - 1) ar1 = nrows - 1;
  const size_t as0 = GATHER ? (size_t)(offs[e] + ar0) : (size_t)ar0;  // s rows contiguous
  const size_t as1 = GATHER ? (size_t)(offs[e] + ar1) : (size_t)ar1;
  const u16* aSrc0 = s_in + as0 * Fdim + sc * 8;
  const u16* aSrc1 = s_in + as1 * Fdim + sc * 8;
  const u16* bSrc0 = wd_t + (size_t)e * Hdim * Fdim + (size_t)(n0 + sr0) * Fdim + sc * 8;
  const u16* bSrc1 = wd_t + (size_t)e * Hdim * Fdim + (size_t)(n0 + sr0 + 64) * Fdim + sc * 8;

  const int wm = (wave & 1) * 64, wn = (wave >> 1) * 64;
  const int lrow = lane & 15, lc = lane >> 4;

  int oA[4], oB[4];
#pragma unroll
  for (int mt = 0; mt < 4; mt++) {
    int r = wm + mt * 16 + lrow;
    oA[mt] = (r * 4 + (lc ^ ((r >> 1) & 3))) * 8;
  }
#pragma unroll
  for (int nt = 0; nt < 4; nt++) {
    int r = wn + nt * 16 + lrow;
    oB[nt] = (r * 4 + (lc ^ ((r >> 1) & 3))) * 8;
  }

  f32x4 zero = {0.f, 0.f, 0.f, 0.f};
  f32x4 acc[4][4];
#pragma unroll
  for (int mt = 0; mt < 4; mt++)
#pragma unroll
    for (int nt = 0; nt < 4; nt++) acc[mt][nt] = zero;

#define STAGE2(buf, k)                                          \
  do {                                                          \
    gload16(aSrc0 + (k), lA + (buf) * 4096 + aOffW);            \
    gload16(aSrc1 + (k), lA + (buf) * 4096 + 2048 + aOffW);     \
    gload16(bSrc0 + (k), lB + (buf) * 4096 + aOffW);            \
    gload16(bSrc1 + (k), lB + (buf) * 4096 + 2048 + aOffW);     \
  } while (0)

#define COMP2(buf)                                              \
  do {                                                          \
    const u16* bA = lA + (buf) * 4096;                          \
    const u16* bB = lB + (buf) * 4096;                          \
    bf16x8 af[4], bf[4];                                        \
    _Pragma("unroll")                                           \
    for (int mt = 0; mt < 4; mt++) af[mt] = *(const bf16x8*)(bA + oA[mt]); \
    _Pragma("unroll")                                           \
    for (int nt = 0; nt < 4; nt++) bf[nt] = *(const bf16x8*)(bB + oB[nt]); \
    _Pragma("unroll")                                           \
    for (int mt = 0; mt < 4; mt++)                              \
      _Pragma("unroll")                                         \
      for (int nt = 0; nt < 4; nt++)                            \
        acc[mt][nt] = MFMA16(af[mt], bf[nt], acc[mt][nt]);      \
  } while (0)

  STAGE2(0, 0);
  __syncthreads();
  int cur = 0;
  for (int k0 = 0; k0 < Fdim - 32; k0 += 32) {
    STAGE2(cur ^ 1, k0 + 32);
    COMP2(cur);
    __syncthreads();
    cur ^= 1;
  }
  COMP2(cur);

#undef STAGE2
#undef COMP2

#pragma unroll
  for (int mt = 0; mt < 4; mt++)
#pragma unroll
    for (int nt = 0; nt < 4; nt++)
#pragma unroll
      for (int r = 0; r < 4; r++) {
        int row = wm + mt * 16 + (lane >> 4) * 4 + r;
        if (m0 + row < nrows) {
          int col = n0 + wn + nt * 16 + (lane & 15);
          float v = acc[mt][nt][r];
          if (GATHER) {
            int t = tok_list[(size_t)e * Tdim + m0 + row];
            float w = wt_list[(size_t)e * Tdim + m0 + row];
            atomicAdd(out + (size_t)t * Hdim + col, v * w);
          } else {
            out[(size_t)(m0 + row) * Hdim + col] = v;
          }
        }
      }
}

// ---------------- launch ----------------
extern "C" void kernel_launch(void* const* d_in, const int* in_sizes, int n_in,
                              void* d_out, int out_size, void* d_ws, size_t ws_size,
                              hipStream_t stream) {
  const float* x      = (const float*)d_in[0];
  const float* gate_w = (const float*)d_in[1];
  const float* wg     = (const float*)d_in[2];
  const float* wu     = (const float*)d_in[3];
  const float* wd     = (const float*)d_in[4];
  const float* sg     = (const float*)d_in[5];
  const float* su     = (const float*)d_in[6];
  const float* sd     = (const float*)d_in[7];
  float* out = (float*)d_out;
  char* ws = (char*)d_ws;

  // common small buffers
  constexpr size_t O_COUNTS = 0;     // 64 B
  constexpr size_t O_ZOFF   = 64;    // 64 B of zeros (phased-mode "offs")
  constexpr size_t O_OFFS   = 128;   // 64 B
  constexpr size_t O_TOK    = 256;
  constexpr size_t O_WT     = O_TOK + sizeof(int) * (size_t)Edim * Tdim;
  constexpr size_t O_XBF    = O_WT + sizeof(float) * (size_t)Edim * Tdim;
  constexpr size_t O_AFTER  = O_XBF + 2ull * Tdim * Hdim;

  constexpr size_t SZ_EHF = 2ull * Hdim * Fdim;           // one expert matrix, bf16
  // batched layout
  constexpr size_t B_WGT = O_AFTER;
  constexpr size_t B_WUT = B_WGT + SZ_EHF * Edim;
  constexpr size_t B_WDT = B_WUT + SZ_EHF * Edim;
  constexpr size_t B_SGT = B_WDT + SZ_EHF * Edim;
  constexpr size_t B_SUT = B_SGT + SZ_EHF;
  constexpr size_t B_SDT = B_SUT + SZ_EHF;
  constexpr size_t B_SRT = B_SDT + SZ_EHF;                // routed s: [2T][F]
  constexpr size_t B_SSH = B_SRT + 2ull * 2 * Tdim * Fdim;
  constexpr size_t B_END = B_SSH + 2ull * Tdim * Fdim;    // ~218 MiB

  // phased layout (per-expert reuse)
  constexpr size_t P_A = O_AFTER;
  constexpr size_t P_B = P_A + SZ_EHF;
  constexpr size_t P_D = P_B + SZ_EHF;
  constexpr size_t P_S = P_D + SZ_EHF;                    // s: [T][F]

  int*   counts = (int*)(ws + O_COUNTS);
  int*   zoff   = (int*)(ws + O_ZOFF);
  int*   offs   = (int*)(ws + O_OFFS);
  int*   tok    = (int*)(ws + O_TOK);
  float* wt     = (float*)(ws + O_WT);
  u16*   xbf    = (u16*)(ws + O_XBF);

  hipMemsetAsync(ws, 0, 256, stream);  // zero counts + zoff (+offs, rewritten by scan)
  gate_k<<<Tdim, 64, 0, stream>>>(x, gate_w, xbf, counts, tok, wt);
  scan_k<<<1, 64, 0, stream>>>(counts, offs);

  if (ws_size >= B_END) {
    // ---------------- batched path ----------------
    u16* wg_t = (u16*)(ws + B_WGT);
    u16* wu_t = (u16*)(ws + B_WUT);
    u16* wd_t = (u16*)(ws + B_WDT);
    u16* sg_t = (u16*)(ws + B_SGT);
    u16* su_t = (u16*)(ws + B_SUT);
    u16* sd_t = (u16*)(ws + B_SDT);
    u16* s_rt = (u16*)(ws + B_SRT);
    u16* s_sh = (u16*)(ws + B_SSH);

    transpose_k<<<dim3(Fdim / 64, Hdim / 64, Edim), 256, 0, stream>>>(wg, wg_t, Hdim, Fdim);
    transpose_k<<<dim3(Fdim / 64, Hdim / 64, Edim), 256, 0, stream>>>(wu, wu_t, Hdim, Fdim);
    transpose_k<<<dim3(Hdim / 64, Fdim / 64, Edim), 256, 0, stream>>>(wd, wd_t, Fdim, Hdim);
    transpose_k<<<dim3(Fdim / 64, Hdim / 64, 1), 256, 0, stream>>>(sg, sg_t, Hdim, Fdim);
    transpose_k<<<dim3(Fdim / 64, Hdim / 64, 1), 256, 0, stream>>>(su, su_t, Hdim, Fdim);
    transpose_k<<<dim3(Hdim / 64, Fdim / 64, 1), 256, 0, stream>>>(sd, sd_t, Fdim, Hdim);

    gemm1_k<false><<<dim3(Tdim / 128, Fdim / 64, 1), 256, 0, stream>>>(
        xbf, sg_t, su_t, tok, counts, offs, s_sh, 0);
    gemm1_k<true><<<dim3(Tdim / 128, Fdim / 64, Edim), 256, 0, stream>>>(
        xbf, wg_t, wu_t, tok, counts, offs, s_rt, 0);

    gemm2_k<false><<<dim3(Tdim / 128, Hdim / 128, 1), 256, 0, stream>>>(
        s_sh, sd_t, tok, counts, offs, wt, out, 0);
    gemm2_k<true><<<dim3(Tdim / 128, Hdim / 128, Edim), 256, 0, stream>>>(
        s_rt, wd_t, tok, counts, offs, wt, out, 0);
  } else {
    // ---------------- phased path (per-expert buffer reuse, ~46 MiB) ----------------
    u16* A = (u16*)(ws + P_A);
    u16* Bb = (u16*)(ws + P_B);
    u16* D = (u16*)(ws + P_D);
    u16* S = (u16*)(ws + P_S);

    // shared expert
    transpose_k<<<dim3(Fdim / 64, Hdim / 64, 1), 256, 0, stream>>>(sg, A, Hdim, Fdim);
    transpose_k<<<dim3(Fdim / 64, Hdim / 64, 1), 256, 0, stream>>>(su, Bb, Hdim, Fdim);
    transpose_k<<<dim3(Hdim / 64, Fdim / 64, 1), 256, 0, stream>>>(sd, D, Fdim, Hdim);
    gemm1_k<false><<<dim3(Tdim / 128, Fdim / 64, 1), 256, 0, stream>>>(
        xbf, A, Bb, tok, counts, offs, S, 0);
    gemm2_k<false><<<dim3(Tdim / 128, Hdim / 128, 1), 256, 0, stream>>>(
        S, D, tok, counts, offs, wt, out, 0);

    // routed experts, one at a time; zoff (all zeros) makes S per-expert-local.
    for (int e = 0; e < Edim; e++) {
      const size_t weoff = (size_t)e * Hdim * Fdim;
      transpose_k<<<dim3(Fdim / 64, Hdim / 64, 1), 256, 0, stream>>>(wg + weoff, A, Hdim, Fdim);
      transpose_k<<<dim3(Fdim / 64, Hdim / 64, 1), 256, 0, stream>>>(wu + weoff, Bb, Hdim, Fdim);
      transpose_k<<<dim3(Hdim / 64, Fdim / 64, 1), 256, 0, stream>>>(wd + weoff, D, Fdim, Hdim);
      // kernel reads counts[e]/tok[e*T..] via e = e_base + 0; S indexed from 0 via zoff
      gemm1_k<true><<<dim3(Tdim / 128, Fdim / 64, 1), 256, 0, stream>>>(
          xbf, A - weoff, Bb - weoff, tok, counts, zoff, S, e);
      gemm2_k<true><<<dim3(Tdim / 128, Hdim / 128, 1), 256, 0, stream>>>(
          S, D - weoff, tok, counts, zoff, wt, out, e);
    }
  }

  (void)in_sizes; (void)n_in; (void)out_size; (void)ws_size;
}

// Round 5
// 1314.871 us; speedup vs baseline: 1.0557x; 1.0346x over previous
//
#include <hip/hip_runtime.h>

// MoE FFN: top-2 of 8 routed SwiGLU experts + shared expert.
// T=4096 tokens, H=1024, F=2752. fp32 in/out, bf16 MFMA internally.
// R5 (= R4 re-run; container infra flake, same precedent as R2->R3):
//     counted-vmcnt pipeline (T4): raw s_barrier (no implicit drain),
//     s_waitcnt vmcnt(4) at TOP of next iter -> prefetch loads stay in
//     flight across the barrier with a full iteration of latency cover.
//     XOR-swizzled LDS chunks (0 conflicts, verified R1).

#define Hdim 1024
#define Fdim 2752
#define Edim 8
#define Tdim 4096

typedef unsigned short u16;
typedef __bf16 bf16x8 __attribute__((ext_vector_type(8)));
typedef float f32x4 __attribute__((ext_vector_type(4)));

#define MFMA16(a, b, c) __builtin_amdgcn_mfma_f32_16x16x32_bf16(a, b, c, 0, 0, 0)

__device__ __forceinline__ u16 f2bf(float f) {  // fp32 -> bf16 bits, RNE
  unsigned u = __float_as_uint(f);
  u += 0x7fffu + ((u >> 16) & 1u);
  return (u16)(u >> 16);
}

// async global->LDS, 16B per lane. LDS dest is wave-uniform base + lane*16.
__device__ __forceinline__ void gload16(const u16* g, u16* l) {
  __builtin_amdgcn_global_load_lds((const __attribute__((address_space(1))) void*)g,
                                   (__attribute__((address_space(3))) void*)l, 16, 0, 0);
}

// wait for all but the newest N VMEM ops; fence the scheduler afterwards (rule #18)
#define VMCNT(N)                                            \
  do {                                                      \
    asm volatile("s_waitcnt vmcnt(" #N ")" ::: "memory");   \
    __builtin_amdgcn_sched_barrier(0);                      \
  } while (0)

// ---------- transpose + convert: src[R][C] fp32 -> dst[C][R] bf16 ----------
__global__ __launch_bounds__(256) void transpose_k(const float* __restrict__ src,
                                                   u16* __restrict__ dst, int R, int C) {
  __shared__ float tile[64][65];
  const size_t zoff = (size_t)blockIdx.z * R * C;
  src += zoff; dst += zoff;
  const int r0 = blockIdx.y * 64, c0 = blockIdx.x * 64;
  const int tx = threadIdx.x & 63, ty = threadIdx.x >> 6;
#pragma unroll
  for (int i = 0; i < 16; i++) {
    int row = ty * 16 + i;
    tile[row][tx] = src[(size_t)(r0 + row) * C + (c0 + tx)];
  }
  __syncthreads();
#pragma unroll
  for (int i = 0; i < 16; i++) {
    int crow = ty * 16 + i;
    dst[(size_t)(c0 + crow) * R + (r0 + tx)] = f2bf(tile[tx][crow]);
  }
}

// ---------- gate: exact fp32 softmax top-2, build gather lists; x -> bf16 ----------
__global__ __launch_bounds__(64) void gate_k(const float* __restrict__ x,
                                             const float* __restrict__ gw,
                                             u16* __restrict__ xbf,
                                             int* __restrict__ counts,
                                             int* __restrict__ tok,
                                             float* __restrict__ wt) {
  const int t = blockIdx.x, lane = threadIdx.x;
  const float* xr = x + (size_t)t * Hdim;
  float acc[Edim];
#pragma unroll
  for (int e = 0; e < Edim; e++) acc[e] = 0.f;
  for (int i = 0; i < Hdim / 64; i++) {
    int idx = i * 64 + lane;
    float xv = xr[idx];
    xbf[(size_t)t * Hdim + idx] = f2bf(xv);
#pragma unroll
    for (int e = 0; e < Edim; e++) acc[e] += xv * gw[e * Hdim + idx];
  }
#pragma unroll
  for (int e = 0; e < Edim; e++)
    for (int o = 32; o > 0; o >>= 1) acc[e] += __shfl_xor(acc[e], o, 64);
  if (lane == 0) {
    float m = acc[0];
    for (int e = 1; e < Edim; e++) m = fmaxf(m, acc[e]);
    float p[Edim], ssum = 0.f;
    for (int e = 0; e < Edim; e++) { p[e] = expf(acc[e] - m); ssum += p[e]; }
    // top-2 on logits (monotone w/ softmax); strict > keeps lowest index on ties (jax top_k)
    int i1 = 0; float l1 = acc[0];
    for (int e = 1; e < Edim; e++) if (acc[e] > l1) { l1 = acc[e]; i1 = e; }
    int i2 = -1; float l2 = -1e30f;
    for (int e = 0; e < Edim; e++) if (e != i1 && acc[e] > l2) { l2 = acc[e]; i2 = e; }
    float s1 = p[i1] / ssum, s2 = p[i2] / ssum;
    float den = s1 + s2 + 1e-20f;
    float w1 = s1 / den, w2 = s2 / den;
    int p1 = atomicAdd(&counts[i1], 1);
    tok[i1 * Tdim + p1] = t; wt[i1 * Tdim + p1] = w1;
    int p2 = atomicAdd(&counts[i2], 1);
    tok[i2 * Tdim + p2] = t; wt[i2 * Tdim + p2] = w2;
  }
}

__global__ void scan_k(const int* __restrict__ counts, int* __restrict__ offs) {
  if (threadIdx.x == 0) {
    int a = 0;
    for (int e = 0; e < Edim; e++) { offs[e] = a; a += counts[e]; }
    offs[Edim] = a;
  }
}

// LDS tile layout: rows of 32 u16 = 64 B = 4 chunks of 16 B.
// chunk (r,c) stored at slot (r, c ^ ((r>>1)&3)).  Involution; linear dest for
// global_load_lds (pre-swizzled SOURCE address), swizzled ds_read address.
// Verified 0 bank conflicts + correct output in R1/R3.

// ---------- GEMM1: s = silu(X@Wg) * (X@Wu), gathered rows, bf16 out ----------
// Block: 128 rows x 64 f-cols (both G and U). 4 waves, each 64x32 of both.
// Counted-vmcnt 2-buffer pipeline: STAGE(t+1) at top; vmcnt(4) waits only
// tile-t loads; raw barriers (no drain).
template <bool GATHER>
__global__ __launch_bounds__(256) void gemm1_k(const u16* __restrict__ xbf,
                                               const u16* __restrict__ wg_t,  // [E][F][H] bf16
                                               const u16* __restrict__ wu_t,
                                               const int* __restrict__ tok_list,
                                               const int* __restrict__ counts,
                                               const int* __restrict__ offs,
                                               u16* __restrict__ s_out,
                                               int e_base) {
  const int e = e_base + blockIdx.z;
  const int nrows = GATHER ? counts[e] : Tdim;
  const int m0 = blockIdx.x * 128;   // m innermost: co-resident blocks share B
  if (m0 >= nrows) return;
  const int n0 = blockIdx.y * 64;
  const int srow0 = GATHER ? (offs[e] + m0) : m0;

  __shared__ __align__(16) u16 lA[2 * 128 * 32];   // 2 x 8 KB
  __shared__ __align__(16) u16 lBG[2 * 64 * 32];   // 2 x 4 KB
  __shared__ __align__(16) u16 lBU[2 * 64 * 32];

  const int tid = threadIdx.x;
  const int wave = tid >> 6, lane = tid & 63;

  // ---- staging geometry ----
  const int ch = wave * 64 + lane;                 // [0,256)
  const int sr0 = ch >> 2;                         // [0,64)
  const int sc = (ch & 3) ^ ((sr0 >> 1) & 3);      // swizzled source chunk
  const int aOffW = wave * 512;                    // wave-uniform LDS elem offset

  int ar0 = m0 + sr0;      if (ar0 > nrows - 1) ar0 = nrows - 1;
  int ar1 = m0 + sr0 + 64; if (ar1 > nrows - 1) ar1 = nrows - 1;
  const int tk0 = GATHER ? tok_list[(size_t)e * Tdim + ar0] : ar0;
  const int tk1 = GATHER ? tok_list[(size_t)e * Tdim + ar1] : ar1;
  const u16* aSrc0 = xbf + (size_t)tk0 * Hdim + sc * 8;
  const u16* aSrc1 = xbf + (size_t)tk1 * Hdim + sc * 8;
  const u16* bgSrc = wg_t + (size_t)e * Fdim * Hdim + (size_t)(n0 + sr0) * Hdim + sc * 8;
  const u16* buSrc = wu_t + (size_t)e * Fdim * Hdim + (size_t)(n0 + sr0) * Hdim + sc * 8;

  // ---- compute geometry ----
  const int wm = (wave & 1) * 64, wn = (wave >> 1) * 32;
  const int lrow = lane & 15, lc = lane >> 4;      // fragment row-in-16, K-chunk

  int oA[4], oB[2];
#pragma unroll
  for (int mt = 0; mt < 4; mt++) {
    int r = wm + mt * 16 + lrow;
    oA[mt] = (r * 4 + (lc ^ ((r >> 1) & 3))) * 8;
  }
#pragma unroll
  for (int nt = 0; nt < 2; nt++) {
    int r = wn + nt * 16 + lrow;
    oB[nt] = (r * 4 + (lc ^ ((r >> 1) & 3))) * 8;
  }

  f32x4 zero = {0.f, 0.f, 0.f, 0.f};
  f32x4 accG[4][2], accU[4][2];
#pragma unroll
  for (int mt = 0; mt < 4; mt++)
#pragma unroll
    for (int nt = 0; nt < 2; nt++) { accG[mt][nt] = zero; accU[mt][nt] = zero; }

#define STAGE1(buf, k)                                          \
  do {                                                          \
    gload16(aSrc0 + (k), lA + (buf) * 4096 + aOffW);            \
    gload16(aSrc1 + (k), lA + (buf) * 4096 + 2048 + aOffW);     \
    gload16(bgSrc + (k), lBG + (buf) * 2048 + aOffW);           \
    gload16(buSrc + (k), lBU + (buf) * 2048 + aOffW);           \
  } while (0)

#define COMP1(buf)                                              \
  do {                                                          \
    const u16* bA = lA + (buf) * 4096;                          \
    const u16* bG = lBG + (buf) * 2048;                         \
    const u16* bU = lBU + (buf) * 2048;                         \
    bf16x8 af[4], bg[2], bu[2];                                 \
    _Pragma("unroll")                                           \
    for (int mt = 0; mt < 4; mt++) af[mt] = *(const bf16x8*)(bA + oA[mt]); \
    _Pragma("unroll")                                           \
    for (int nt = 0; nt < 2; nt++) {                            \
      bg[nt] = *(const bf16x8*)(bG + oB[nt]);                   \
      bu[nt] = *(const bf16x8*)(bU + oB[nt]);                   \
    }                                                           \
    _Pragma("unroll")                                           \
    for (int mt = 0; mt < 4; mt++)                              \
      _Pragma("unroll")                                         \
      for (int nt = 0; nt < 2; nt++) {                          \
        accG[mt][nt] = MFMA16(af[mt], bg[nt], accG[mt][nt]);    \
        accU[mt][nt] = MFMA16(af[mt], bu[nt], accU[mt][nt]);    \
      }                                                         \
  } while (0)

  // prologue: stage tile 0 (4 loads in flight)
  STAGE1(0, 0);
  int cur = 0;
  for (int k0 = 0; k0 < Hdim - 32; k0 += 32) {
    STAGE1(cur ^ 1, k0 + 32);          // issue next tile: 8 in flight
    VMCNT(4);                          // tile k0 landed (oldest 4); next stays in flight
    __builtin_amdgcn_s_barrier();      // block-wide: tile k0 ready in LDS
    COMP1(cur);                        // ds_read (compiler lgkmcnt) + MFMA
    __builtin_amdgcn_s_barrier();      // all reads done before next STAGE overwrites
    cur ^= 1;
  }
  VMCNT(0);                            // last tile landed
  __builtin_amdgcn_s_barrier();
  COMP1(cur);

#undef STAGE1
#undef COMP1

  // epilogue: silu(g)*u -> bf16
#pragma unroll
  for (int mt = 0; mt < 4; mt++)
#pragma unroll
    for (int nt = 0; nt < 2; nt++)
#pragma unroll
      for (int r = 0; r < 4; r++) {
        int row = wm + mt * 16 + (lane >> 4) * 4 + r;
        if (m0 + row < nrows) {
          float g = accG[mt][nt][r], u = accU[mt][nt][r];
          float sv = g * (1.0f / (1.0f + __expf(-g))) * u;
          s_out[(size_t)(srow0 + row) * Fdim + (n0 + wn + nt * 16 + (lane & 15))] = f2bf(sv);
        }
      }
}

// ---------- GEMM2: Y = s @ Wd; routed: atomicAdd(out, w*Y); shared: store ----------
template <bool GATHER>
__global__ __launch_bounds__(256) void gemm2_k(const u16* __restrict__ s_in,
                                               const u16* __restrict__ wd_t,  // [E][H][F] bf16
                                               const int* __restrict__ tok_list,
                                               const int* __restrict__ counts,
                                               const int* __restrict__ offs,
                                               const float* __restrict__ wt_list,
                                               float* __restrict__ out,
                                               int e_base) {
  const int e = e_base + blockIdx.z;
  const int nrows = GATHER ? counts[e] : Tdim;
  const int m0 = blockIdx.x * 128;
  if (m0 >= nrows) return;
  const int n0 = blockIdx.y * 128;

  __shared__ __align__(16) u16 lA[2 * 128 * 32];
  __shared__ __align__(16) u16 lB[2 * 128 * 32];

  const int tid = threadIdx.x;
  const int wave = tid >> 6, lane = tid & 63;

  const int ch = wave * 64 + lane;
  const int sr0 = ch >> 2;
  const int sc = (ch & 3) ^ ((sr0 >> 1) & 3);
  const int aOffW = wave * 512;

  int ar0 = m0 + sr0;      if (ar0 > nrows - 1) ar0 = nrows - 1;
  int ar1 = m0 + sr0 + 64; if (ar1 > nrows - 1) ar1 = nrows - 1;
  const size_t as0 = GATHER ? (size_t)(offs[e] + ar0) : (size_t)ar0;  // s rows contiguous
  const size_t as1 = GATHER ? (size_t)(offs[e] + ar1) : (size_t)ar1;
  const u16* aSrc0 = s_in + as0 * Fdim + sc * 8;
  const u16* aSrc1 = s_in + as1 * Fdim + sc * 8;
  const u16* bSrc0 = wd_t + (size_t)e * Hdim * Fdim + (size_t)(n0 + sr0) * Fdim + sc * 8;
  const u16* bSrc1 = wd_t + (size_t)e * Hdim * Fdim + (size_t)(n0 + sr0 + 64) * Fdim + sc * 8;

  const int wm = (wave & 1) * 64, wn = (wave >> 1) * 64;
  const int lrow = lane & 15, lc = lane >> 4;

  int oA[4], oB[4];
#pragma unroll
  for (int mt = 0; mt < 4; mt++) {
    int r = wm + mt * 16 + lrow;
    oA[mt] = (r * 4 + (lc ^ ((r >> 1) & 3))) * 8;
  }
#pragma unroll
  for (int nt = 0; nt < 4; nt++) {
    int r = wn + nt * 16 + lrow;
    oB[nt] = (r * 4 + (lc ^ ((r >> 1) & 3))) * 8;
  }

  f32x4 zero = {0.f, 0.f, 0.f, 0.f};
  f32x4 acc[4][4];
#pragma unroll
  for (int mt = 0; mt < 4; mt++)
#pragma unroll
    for (int nt = 0; nt < 4; nt++) acc[mt][nt] = zero;

#define STAGE2(buf, k)                                          \
  do {                                                          \
    gload16(aSrc0 + (k), lA + (buf) * 4096 + aOffW);            \
    gload16(aSrc1 + (k), lA + (buf) * 4096 + 2048 + aOffW);     \
    gload16(bSrc0 + (k), lB + (buf) * 4096 + aOffW);            \
    gload16(bSrc1 + (k), lB + (buf) * 4096 + 2048 + aOffW);     \
  } while (0)

#define COMP2(buf)                                              \
  do {                                                          \
    const u16* bA = lA + (buf) * 4096;                          \
    const u16* bB = lB + (buf) * 4096;                          \
    bf16x8 af[4], bf[4];                                        \
    _Pragma("unroll")                                           \
    for (int mt = 0; mt < 4; mt++) af[mt] = *(const bf16x8*)(bA + oA[mt]); \
    _Pragma("unroll")                                           \
    for (int nt = 0; nt < 4; nt++) bf[nt] = *(const bf16x8*)(bB + oB[nt]); \
    _Pragma("unroll")                                           \
    for (int mt = 0; mt < 4; mt++)                              \
      _Pragma("unroll")                                         \
      for (int nt = 0; nt < 4; nt++)                            \
        acc[mt][nt] = MFMA16(af[mt], bf[nt], acc[mt][nt]);      \
  } while (0)

  STAGE2(0, 0);
  int cur = 0;
  for (int k0 = 0; k0 < Fdim - 32; k0 += 32) {
    STAGE2(cur ^ 1, k0 + 32);
    VMCNT(4);
    __builtin_amdgcn_s_barrier();
    COMP2(cur);
    __builtin_amdgcn_s_barrier();
    cur ^= 1;
  }
  VMCNT(0);
  __builtin_amdgcn_s_barrier();
  COMP2(cur);

#undef STAGE2
#undef COMP2

#pragma unroll
  for (int mt = 0; mt < 4; mt++)
#pragma unroll
    for (int nt = 0; nt < 4; nt++)
#pragma unroll
      for (int r = 0; r < 4; r++) {
        int row = wm + mt * 16 + (lane >> 4) * 4 + r;
        if (m0 + row < nrows) {
          int col = n0 + wn + nt * 16 + (lane & 15);
          float v = acc[mt][nt][r];
          if (GATHER) {
            int t = tok_list[(size_t)e * Tdim + m0 + row];
            float w = wt_list[(size_t)e * Tdim + m0 + row];
            atomicAdd(out + (size_t)t * Hdim + col, v * w);
          } else {
            out[(size_t)(m0 + row) * Hdim + col] = v;
          }
        }
      }
}

// ---------------- launch ----------------
extern "C" void kernel_launch(void* const* d_in, const int* in_sizes, int n_in,
                              void* d_out, int out_size, void* d_ws, size_t ws_size,
                              hipStream_t stream) {
  const float* x      = (const float*)d_in[0];
  const float* gate_w = (const float*)d_in[1];
  const float* wg     = (const float*)d_in[2];
  const float* wu     = (const float*)d_in[3];
  const float* wd     = (const float*)d_in[4];
  const float* sg     = (const float*)d_in[5];
  const float* su     = (const float*)d_in[6];
  const float* sd     = (const float*)d_in[7];
  float* out = (float*)d_out;
  char* ws = (char*)d_ws;

  // common small buffers
  constexpr size_t O_COUNTS = 0;     // 64 B
  constexpr size_t O_ZOFF   = 64;    // 64 B of zeros (phased-mode "offs")
  constexpr size_t O_OFFS   = 128;   // 64 B
  constexpr size_t O_TOK    = 256;
  constexpr size_t O_WT     = O_TOK + sizeof(int) * (size_t)Edim * Tdim;
  constexpr size_t O_XBF    = O_WT + sizeof(float) * (size_t)Edim * Tdim;
  constexpr size_t O_AFTER  = O_XBF + 2ull * Tdim * Hdim;

  constexpr size_t SZ_EHF = 2ull * Hdim * Fdim;           // one expert matrix, bf16
  // batched layout
  constexpr size_t B_WGT = O_AFTER;
  constexpr size_t B_WUT = B_WGT + SZ_EHF * Edim;
  constexpr size_t B_WDT = B_WUT + SZ_EHF * Edim;
  constexpr size_t B_SGT = B_WDT + SZ_EHF * Edim;
  constexpr size_t B_SUT = B_SGT + SZ_EHF;
  constexpr size_t B_SDT = B_SUT + SZ_EHF;
  constexpr size_t B_SRT = B_SDT + SZ_EHF;                // routed s: [2T][F]
  constexpr size_t B_SSH = B_SRT + 2ull * 2 * Tdim * Fdim;
  constexpr size_t B_END = B_SSH + 2ull * Tdim * Fdim;    // ~218 MiB

  // phased layout (per-expert reuse)
  constexpr size_t P_A = O_AFTER;
  constexpr size_t P_B = P_A + SZ_EHF;
  constexpr size_t P_D = P_B + SZ_EHF;
  constexpr size_t P_S = P_D + SZ_EHF;                    // s: [T][F]

  int*   counts = (int*)(ws + O_COUNTS);
  int*   zoff   = (int*)(ws + O_ZOFF);
  int*   offs   = (int*)(ws + O_OFFS);
  int*   tok    = (int*)(ws + O_TOK);
  float* wt     = (float*)(ws + O_WT);
  u16*   xbf    = (u16*)(ws + O_XBF);

  hipMemsetAsync(ws, 0, 256, stream);  // zero counts + zoff (+offs, rewritten by scan)
  gate_k<<<Tdim, 64, 0, stream>>>(x, gate_w, xbf, counts, tok, wt);
  scan_k<<<1, 64, 0, stream>>>(counts, offs);

  if (ws_size >= B_END) {
    // ---------------- batched path ----------------
    u16* wg_t = (u16*)(ws + B_WGT);
    u16* wu_t = (u16*)(ws + B_WUT);
    u16* wd_t = (u16*)(ws + B_WDT);
    u16* sg_t = (u16*)(ws + B_SGT);
    u16* su_t = (u16*)(ws + B_SUT);
    u16* sd_t = (u16*)(ws + B_SDT);
    u16* s_rt = (u16*)(ws + B_SRT);
    u16* s_sh = (u16*)(ws + B_SSH);

    transpose_k<<<dim3(Fdim / 64, Hdim / 64, Edim), 256, 0, stream>>>(wg, wg_t, Hdim, Fdim);
    transpose_k<<<dim3(Fdim / 64, Hdim / 64, Edim), 256, 0, stream>>>(wu, wu_t, Hdim, Fdim);
    transpose_k<<<dim3(Hdim / 64, Fdim / 64, Edim), 256, 0, stream>>>(wd, wd_t, Fdim, Hdim);
    transpose_k<<<dim3(Fdim / 64, Hdim / 64, 1), 256, 0, stream>>>(sg, sg_t, Hdim, Fdim);
    transpose_k<<<dim3(Fdim / 64, Hdim / 64, 1), 256, 0, stream>>>(su, su_t, Hdim, Fdim);
    transpose_k<<<dim3(Hdim / 64, Fdim / 64, 1), 256, 0, stream>>>(sd, sd_t, Fdim, Hdim);

    gemm1_k<false><<<dim3(Tdim / 128, Fdim / 64, 1), 256, 0, stream>>>(
        xbf, sg_t, su_t, tok, counts, offs, s_sh, 0);
    gemm1_k<true><<<dim3(Tdim / 128, Fdim / 64, Edim), 256, 0, stream>>>(
        xbf, wg_t, wu_t, tok, counts, offs, s_rt, 0);

    gemm2_k<false><<<dim3(Tdim / 128, Hdim / 128, 1), 256, 0, stream>>>(
        s_sh, sd_t, tok, counts, offs, wt, out, 0);
    gemm2_k<true><<<dim3(Tdim / 128, Hdim / 128, Edim), 256, 0, stream>>>(
        s_rt, wd_t, tok, counts, offs, wt, out, 0);
  } else {
    // ---------------- phased path (per-expert buffer reuse, ~46 MiB) ----------------
    u16* A = (u16*)(ws + P_A);
    u16* Bb = (u16*)(ws + P_B);
    u16* D = (u16*)(ws + P_D);
    u16* S = (u16*)(ws + P_S);

    // shared expert
    transpose_k<<<dim3(Fdim / 64, Hdim / 64, 1), 256, 0, stream>>>(sg, A, Hdim, Fdim);
    transpose_k<<<dim3(Fdim / 64, Hdim / 64, 1), 256, 0, stream>>>(su, Bb, Hdim, Fdim);
    transpose_k<<<dim3(Hdim / 64, Fdim / 64, 1), 256, 0, stream>>>(sd, D, Fdim, Hdim);
    gemm1_k<false><<<dim3(Tdim / 128, Fdim / 64, 1), 256, 0, stream>>>(
        xbf, A, Bb, tok, counts, offs, S, 0);
    gemm2_k<false><<<dim3(Tdim / 128, Hdim / 128, 1), 256, 0, stream>>>(
        S, D, tok, counts, offs, wt, out, 0);

    // routed experts, one at a time; zoff (all zeros) makes S per-expert-local.
    for (int e = 0; e < Edim; e++) {
      const size_t weoff = (size_t)e * Hdim * Fdim;
      transpose_k<<<dim3(Fdim / 64, Hdim / 64, 1), 256, 0, stream>>>(wg + weoff, A, Hdim, Fdim);
      transpose_k<<<dim3(Fdim / 64, Hdim / 64, 1), 256, 0, stream>>>(wu + weoff, Bb, Hdim, Fdim);
      transpose_k<<<dim3(Hdim / 64, Fdim / 64, 1), 256, 0, stream>>>(wd + weoff, D, Fdim, Hdim);
      // kernel reads counts[e]/tok[e*T..] via e = e_base + 0; S indexed from 0 via zoff
      gemm1_k<true><<<dim3(Tdim / 128, Fdim / 64, 1), 256, 0, stream>>>(
          xbf, A - weoff, Bb - weoff, tok, counts, zoff, S, e);
      gemm2_k<true><<<dim3(Tdim / 128, Hdim / 128, 1), 256, 0, stream>>>(
          S, D - weoff, tok, counts, zoff, wt, out, e);
    }
  }

  (void)in_sizes; (void)n_in; (void)out_size; (void)ws_size;
}